// Round 2
// baseline (224.383 us; speedup 1.0000x reference)
//
#include <hip/hip_runtime.h>
#include <hip/hip_bf16.h>
#include <cstdint>
#include <cstddef>

#define NN 8192
#define FIN 256
#define FO 128

typedef float f32x4 __attribute__((ext_vector_type(4)));
typedef __bf16 bf16x8 __attribute__((ext_vector_type(8)));

__device__ __forceinline__ unsigned enc_f32(float f) {
  unsigned u = __float_as_uint(f);
  return (u & 0x80000000u) ? ~u : (u | 0x80000000u);
}
__device__ __forceinline__ float dec_f32(unsigned u) {
  unsigned b = (u & 0x80000000u) ? (u ^ 0x80000000u) : ~u;
  return __uint_as_float(b);
}

// ---------------- K1: h = x @ W  (8192x256 @ 256x128) ----------------
__global__ void k1_xw(const float* __restrict__ x, const float* __restrict__ W,
                      float* __restrict__ h, unsigned* __restrict__ enc) {
  __shared__ float xs[32 * 66];
  __shared__ float Ws[64 * 128];
  int t = threadIdx.x;
  int r0 = blockIdx.x * 32;
  if (blockIdx.x == 0 && t == 0) *enc = 0u;  // init for K2's atomicMax
  int r = t & 31, cg = t >> 5;
  float acc[16];
#pragma unroll
  for (int i = 0; i < 16; ++i) acc[i] = 0.f;
  for (int ko = 0; ko < 4; ++ko) {
    __syncthreads();
    {
      int rr = t >> 3, kc = (t & 7) * 8;
      const float2* src = (const float2*)(x + (size_t)(r0 + rr) * FIN + ko * 64 + kc);
      float2* dst = (float2*)&xs[rr * 66 + kc];
#pragma unroll
      for (int q = 0; q < 4; ++q) dst[q] = src[q];
    }
    {
      int kk = t >> 2, q = t & 3;
      const float4* src = (const float4*)(W + (size_t)(ko * 64 + kk) * FO + q * 32);
      float4* dst = (float4*)&Ws[kk * 128 + q * 32];
#pragma unroll
      for (int i = 0; i < 8; ++i) dst[i] = src[i];
    }
    __syncthreads();
#pragma unroll 8
    for (int kk = 0; kk < 64; ++kk) {
      float xv = xs[r * 66 + kk];
      const float4* wr = (const float4*)&Ws[kk * 128 + cg * 16];
      float4 w0 = wr[0], w1 = wr[1], w2 = wr[2], w3 = wr[3];
      acc[0]  = fmaf(xv, w0.x, acc[0]);  acc[1]  = fmaf(xv, w0.y, acc[1]);
      acc[2]  = fmaf(xv, w0.z, acc[2]);  acc[3]  = fmaf(xv, w0.w, acc[3]);
      acc[4]  = fmaf(xv, w1.x, acc[4]);  acc[5]  = fmaf(xv, w1.y, acc[5]);
      acc[6]  = fmaf(xv, w1.z, acc[6]);  acc[7]  = fmaf(xv, w1.w, acc[7]);
      acc[8]  = fmaf(xv, w2.x, acc[8]);  acc[9]  = fmaf(xv, w2.y, acc[9]);
      acc[10] = fmaf(xv, w2.z, acc[10]); acc[11] = fmaf(xv, w2.w, acc[11]);
      acc[12] = fmaf(xv, w3.x, acc[12]); acc[13] = fmaf(xv, w3.y, acc[13]);
      acc[14] = fmaf(xv, w3.z, acc[14]); acc[15] = fmaf(xv, w3.w, acc[15]);
    }
  }
  float* hp = h + (size_t)(r0 + r) * FO + cg * 16;
#pragma unroll
  for (int i = 0; i < 4; ++i)
    ((float4*)hp)[i] = make_float4(acc[4 * i], acc[4 * i + 1], acc[4 * i + 2], acc[4 * i + 3]);
}

// ---------------- K2: hT_hi/lo (bf16 transpose), s1, s2, max(s2) ----------------
__global__ void k2_prep(const float* __restrict__ h, const float* __restrict__ a,
                        __bf16* __restrict__ hT_hi, __bf16* __restrict__ hT_lo,
                        float* __restrict__ s1, float* __restrict__ s2,
                        unsigned* __restrict__ enc) {
  __shared__ float ht[64 * 129];
  int t = threadIdx.x;
  int r0 = blockIdx.x * 64;
  {
    int rr = t >> 2, q = t & 3;
    const float4* src = (const float4*)(h + (size_t)(r0 + rr) * FO + q * 32);
    float* dst = &ht[rr * 129 + q * 32];
#pragma unroll
    for (int i = 0; i < 8; ++i) {
      float4 v = src[i];
      dst[4 * i + 0] = v.x; dst[4 * i + 1] = v.y;
      dst[4 * i + 2] = v.z; dst[4 * i + 3] = v.w;
    }
  }
  __syncthreads();
  {
    int c = t >> 1, half = t & 1;
    alignas(16) unsigned short hi[32];
    alignas(16) unsigned short lo[32];
#pragma unroll
    for (int i = 0; i < 32; ++i) {
      float v = ht[(half * 32 + i) * 129 + c];
      __bf16 bh = (__bf16)v;
      float rr = v - (float)bh;
      __bf16 bl = (__bf16)rr;
      hi[i] = __builtin_bit_cast(unsigned short, bh);
      lo[i] = __builtin_bit_cast(unsigned short, bl);
    }
    int4* dh = (int4*)(hT_hi + (size_t)c * NN + r0 + half * 32);
    int4* dl = (int4*)(hT_lo + (size_t)c * NN + r0 + half * 32);
#pragma unroll
    for (int i = 0; i < 4; ++i) { dh[i] = ((const int4*)hi)[i]; dl[i] = ((const int4*)lo)[i]; }
  }
  if (t < 64) {
    int row = r0 + t;
    float v1 = 0.f, v2 = 0.f;
#pragma unroll 16
    for (int c = 0; c < FO; ++c) {
      float hv = ht[t * 129 + c];
      v1 = fmaf(hv, a[c], v1);
      v2 = fmaf(hv, a[FO + c], v2);
    }
    s1[row] = v1; s2[row] = v2;
    float m = v2;
#pragma unroll
    for (int off = 1; off < 64; off <<= 1) m = fmaxf(m, __shfl_xor(m, off));
    if (t == 0) atomicMax(enc, enc_f32(m));
  }
}

// weight element: w = adj>0 ? exp(leaky(s1+s2) - m) : 0, rounded to bf16;
// sum accumulates the *rounded* weight for exact normalization consistency.
__device__ __forceinline__ __bf16 wel(int av, float s2v, float s1v, float mv, float& sum) {
  float tt = s1v + s2v;
  tt = fmaxf(tt, 0.01f * tt);  // leaky_relu
  float wf = (av > 0) ? __expf(tt - mv) : 0.f;
  __bf16 wb = (__bf16)wf;
  sum += (float)wb;
  return wb;
}

// ---------------- K4: main fused attention x h (split-K, NO LDS, NO BARRIERS) ----
// grid (64, splitk), 256 threads = 4 waves x 32 rows. MFMA 16x16x32 bf16.
// A (weights) computed directly in fragment layout: lane l -> row l&15, k 8*(l>>4)+e.
// B fragments loaded DIRECTLY from global hT (c-major): one bf16x8 per (cf, lane).
__global__ void __launch_bounds__(256) k4_main(
    const int* __restrict__ adj, const float* __restrict__ s1g,
    const float* __restrict__ s2g, const unsigned* __restrict__ enc,
    const __bf16* __restrict__ hT_hi, const __bf16* __restrict__ hT_lo,
    float* __restrict__ num_p, float* __restrict__ den_p, int jchunk) {
  int t = threadIdx.x;
  int l = t & 63, wv = t >> 6;
  int r0 = blockIdx.x * 128;
  int split = blockIdx.y;
  int jbeg = split * jchunk;
  int jend = jbeg + jchunk;
  int l15 = l & 15, kgrp = l >> 4;
  int rowA0 = r0 + wv * 32 + l15;
  int rowA1 = rowA0 + 16;
  float c2 = dec_f32(*enc);
  float s10 = s1g[rowA0], s11 = s1g[rowA1];
  float m0 = s10 + c2; m0 = fmaxf(m0, 0.01f * m0);
  float m1 = s11 + c2; m1 = fmaxf(m1, 0.01f * m1);
  f32x4 acc[2][8];
#pragma unroll
  for (int a2 = 0; a2 < 2; ++a2)
#pragma unroll
    for (int cf = 0; cf < 8; ++cf) acc[a2][cf] = (f32x4){0.f, 0.f, 0.f, 0.f};
  float sum0 = 0.f, sum1 = 0.f;
  const int* adjr0 = adj + (size_t)rowA0 * NN;
  const int* adjr1 = adj + (size_t)rowA1 * NN;
  // B-fragment base: row c = cf*16 + l15, col j = j0 + kgrp*8
  const __bf16* bb_h = hT_hi + (size_t)l15 * NN + kgrp * 8;
  const __bf16* bb_l = hT_lo + (size_t)l15 * NN + kgrp * 8;

  // prefetch first iteration's adj / s2
  int jl = jbeg + kgrp * 8;
  int4 A00 = ((const int4*)(adjr0 + jl))[0];
  int4 A01 = ((const int4*)(adjr0 + jl))[1];
  int4 A10 = ((const int4*)(adjr1 + jl))[0];
  int4 A11 = ((const int4*)(adjr1 + jl))[1];
  float4 sa = *(const float4*)(s2g + jl);
  float4 sb = *(const float4*)(s2g + jl + 4);

  for (int j0 = jbeg; j0 < jend; j0 += 32) {
    // prefetch next iteration (wave-uniform condition, registers only)
    int4 nA00, nA01, nA10, nA11; float4 nsa, nsb;
    if (j0 + 32 < jend) {
      int jn = j0 + 32 + kgrp * 8;
      nA00 = ((const int4*)(adjr0 + jn))[0];
      nA01 = ((const int4*)(adjr0 + jn))[1];
      nA10 = ((const int4*)(adjr1 + jn))[0];
      nA11 = ((const int4*)(adjr1 + jn))[1];
      nsa = *(const float4*)(s2g + jn);
      nsb = *(const float4*)(s2g + jn + 4);
    }
    // attention weights for this 32-j strip, directly in A-fragment layout
    bf16x8 af0, af1;
    af0[0] = wel(A00.x, sa.x, s10, m0, sum0);
    af0[1] = wel(A00.y, sa.y, s10, m0, sum0);
    af0[2] = wel(A00.z, sa.z, s10, m0, sum0);
    af0[3] = wel(A00.w, sa.w, s10, m0, sum0);
    af0[4] = wel(A01.x, sb.x, s10, m0, sum0);
    af0[5] = wel(A01.y, sb.y, s10, m0, sum0);
    af0[6] = wel(A01.z, sb.z, s10, m0, sum0);
    af0[7] = wel(A01.w, sb.w, s10, m0, sum0);
    af1[0] = wel(A10.x, sa.x, s11, m1, sum1);
    af1[1] = wel(A10.y, sa.y, s11, m1, sum1);
    af1[2] = wel(A10.z, sa.z, s11, m1, sum1);
    af1[3] = wel(A10.w, sa.w, s11, m1, sum1);
    af1[4] = wel(A11.x, sb.x, s11, m1, sum1);
    af1[5] = wel(A11.y, sb.y, s11, m1, sum1);
    af1[6] = wel(A11.z, sb.z, s11, m1, sum1);
    af1[7] = wel(A11.w, sb.w, s11, m1, sum1);
    // B fragments straight from global (L1/L2-resident), 16 B each
#pragma unroll
    for (int cf = 0; cf < 8; ++cf) {
      bf16x8 bh = *(const bf16x8*)(bb_h + (size_t)cf * 16 * NN + j0);
      bf16x8 bl = *(const bf16x8*)(bb_l + (size_t)cf * 16 * NN + j0);
      acc[0][cf] = __builtin_amdgcn_mfma_f32_16x16x32_bf16(af0, bh, acc[0][cf], 0, 0, 0);
      acc[0][cf] = __builtin_amdgcn_mfma_f32_16x16x32_bf16(af0, bl, acc[0][cf], 0, 0, 0);
      acc[1][cf] = __builtin_amdgcn_mfma_f32_16x16x32_bf16(af1, bh, acc[1][cf], 0, 0, 0);
      acc[1][cf] = __builtin_amdgcn_mfma_f32_16x16x32_bf16(af1, bl, acc[1][cf], 0, 0, 0);
    }
    A00 = nA00; A01 = nA01; A10 = nA10; A11 = nA11; sa = nsa; sb = nsb;
  }
  // full row sums (lanes l, l^16, l^32, l^48 share a row)
  sum0 += __shfl_xor(sum0, 16); sum0 += __shfl_xor(sum0, 32);
  sum1 += __shfl_xor(sum1, 16); sum1 += __shfl_xor(sum1, 32);
  size_t sbase = (size_t)split * NN;
  if (l < 16) {
    den_p[sbase + r0 + wv * 32 + l] = sum0;
    den_p[sbase + r0 + wv * 32 + 16 + l] = sum1;
  }
  // C/D layout: col = l&15, row = 4*(l>>4)+i
#pragma unroll
  for (int a2 = 0; a2 < 2; ++a2) {
#pragma unroll
    for (int cf = 0; cf < 8; ++cf) {
#pragma unroll
      for (int i = 0; i < 4; ++i) {
        int row = r0 + wv * 32 + a2 * 16 + kgrp * 4 + i;
        int col = cf * 16 + l15;
        num_p[(sbase + row) * (size_t)FO + col] = acc[a2][cf][i];
      }
    }
  }
}

// ---------------- K5: finalize out = elu(sum(num)/sum(den)) ----------------
__global__ void k5_fin(const float* __restrict__ num_p, const float* __restrict__ den_p,
                       float* __restrict__ out, int splitk) {
  int idx = blockIdx.x * 256 + threadIdx.x;
  int row = idx >> 7;
  float num = 0.f, den = 0.f;
  for (int s = 0; s < splitk; ++s) {
    num += num_p[(size_t)s * (NN * FO) + idx];
    den += den_p[(size_t)s * NN + row];
  }
  float v = num / den;
  out[idx] = v > 0.f ? v : expm1f(v);
}

extern "C" void kernel_launch(void* const* d_in, const int* in_sizes, int n_in,
                              void* d_out, int out_size, void* d_ws, size_t ws_size,
                              hipStream_t stream) {
  const float* x   = (const float*)d_in[0];
  const int*   adj = (const int*)d_in[1];
  const float* W   = (const float*)d_in[2];
  const float* a   = (const float*)d_in[3];
  float* out = (float*)d_out;
  char* ws = (char*)d_ws;

  float*    h     = (float*)ws;                                  // 4 MB
  __bf16*   hT_hi = (__bf16*)(ws + ((size_t)4 << 20));           // 2 MB
  __bf16*   hT_lo = (__bf16*)(ws + ((size_t)6 << 20));           // 2 MB
  float*    s1    = (float*)(ws + ((size_t)8 << 20));            // 32 KB
  float*    s2    = (float*)(ws + ((size_t)8 << 20) + (32u << 10));
  unsigned* enc   = (unsigned*)(ws + ((size_t)8 << 20) + (64u << 10));
  float*    den_p = (float*)(ws + ((size_t)8 << 20) + (128u << 10)); // 256 KB max
  float*    num_p = (float*)(ws + ((size_t)9 << 20));            // splitk * 4 MB

  int splitk = 8;
  while (splitk > 1 &&
         ((size_t)9 << 20) + (size_t)splitk * NN * FO * 4 > ws_size)
    splitk >>= 1;
  int jchunk = NN / splitk;

  k1_xw<<<dim3(256), dim3(256), 0, stream>>>(x, W, h, enc);
  k2_prep<<<dim3(128), dim3(256), 0, stream>>>(h, a, hT_hi, hT_lo, s1, s2, enc);
  k4_main<<<dim3(64, splitk), dim3(256), 0, stream>>>(adj, s1, s2, enc, hT_hi, hT_lo,
                                                      num_p, den_p, jchunk);
  k5_fin<<<dim3((NN * FO) / 256), dim3(256), 0, stream>>>(num_p, den_p, out, splitk);
}

// Round 3
// 132.764 us; speedup vs baseline: 1.6901x; 1.6901x over previous
//
#include <hip/hip_runtime.h>
#include <hip/hip_bf16.h>
#include <cstdint>
#include <cstddef>

#define NN 8192
#define FIN 256
#define FO 128

typedef float f32x4 __attribute__((ext_vector_type(4)));
typedef _Float16 f16x8 __attribute__((ext_vector_type(8)));

typedef __attribute__((address_space(3))) void lds_void;
typedef const __attribute__((address_space(1))) void glb_void;
__device__ __forceinline__ void gl_lds16(const void* g, void* l) {
  __builtin_amdgcn_global_load_lds((glb_void*)g, (lds_void*)l, 16, 0, 0);
}

__device__ __forceinline__ unsigned enc_f32(float f) {
  unsigned u = __float_as_uint(f);
  return (u & 0x80000000u) ? ~u : (u | 0x80000000u);
}
__device__ __forceinline__ float dec_f32(unsigned u) {
  unsigned b = (u & 0x80000000u) ? (u ^ 0x80000000u) : ~u;
  return __uint_as_float(b);
}

// ---------------- K1: h = x @ W  (8192x256 @ 256x128) ----------------
__global__ void k1_xw(const float* __restrict__ x, const float* __restrict__ W,
                      float* __restrict__ h, unsigned* __restrict__ enc) {
  __shared__ float xs[32 * 66];
  __shared__ float Ws[64 * 128];
  int t = threadIdx.x;
  int r0 = blockIdx.x * 32;
  if (blockIdx.x == 0 && t == 0) *enc = 0u;  // init for K2's atomicMax
  int r = t & 31, cg = t >> 5;
  float acc[16];
#pragma unroll
  for (int i = 0; i < 16; ++i) acc[i] = 0.f;
  for (int ko = 0; ko < 4; ++ko) {
    __syncthreads();
    {
      int rr = t >> 3, kc = (t & 7) * 8;
      const float2* src = (const float2*)(x + (size_t)(r0 + rr) * FIN + ko * 64 + kc);
      float2* dst = (float2*)&xs[rr * 66 + kc];
#pragma unroll
      for (int q = 0; q < 4; ++q) dst[q] = src[q];
    }
    {
      int kk = t >> 2, q = t & 3;
      const float4* src = (const float4*)(W + (size_t)(ko * 64 + kk) * FO + q * 32);
      float4* dst = (float4*)&Ws[kk * 128 + q * 32];
#pragma unroll
      for (int i = 0; i < 8; ++i) dst[i] = src[i];
    }
    __syncthreads();
#pragma unroll 8
    for (int kk = 0; kk < 64; ++kk) {
      float xv = xs[r * 66 + kk];
      const float4* wr = (const float4*)&Ws[kk * 128 + cg * 16];
      float4 w0 = wr[0], w1 = wr[1], w2 = wr[2], w3 = wr[3];
      acc[0]  = fmaf(xv, w0.x, acc[0]);  acc[1]  = fmaf(xv, w0.y, acc[1]);
      acc[2]  = fmaf(xv, w0.z, acc[2]);  acc[3]  = fmaf(xv, w0.w, acc[3]);
      acc[4]  = fmaf(xv, w1.x, acc[4]);  acc[5]  = fmaf(xv, w1.y, acc[5]);
      acc[6]  = fmaf(xv, w1.z, acc[6]);  acc[7]  = fmaf(xv, w1.w, acc[7]);
      acc[8]  = fmaf(xv, w2.x, acc[8]);  acc[9]  = fmaf(xv, w2.y, acc[9]);
      acc[10] = fmaf(xv, w2.z, acc[10]); acc[11] = fmaf(xv, w2.w, acc[11]);
      acc[12] = fmaf(xv, w3.x, acc[12]); acc[13] = fmaf(xv, w3.y, acc[13]);
      acc[14] = fmaf(xv, w3.z, acc[14]); acc[15] = fmaf(xv, w3.w, acc[15]);
    }
  }
  float* hp = h + (size_t)(r0 + r) * FO + cg * 16;
#pragma unroll
  for (int i = 0; i < 4; ++i)
    ((float4*)hp)[i] = make_float4(acc[4 * i], acc[4 * i + 1], acc[4 * i + 2], acc[4 * i + 3]);
}

// ---------------- K2: hT (fp16 transpose), s1, s2, max(s2) ----------------
__global__ void k2_prep(const float* __restrict__ h, const float* __restrict__ a,
                        _Float16* __restrict__ hT,
                        float* __restrict__ s1, float* __restrict__ s2,
                        unsigned* __restrict__ enc) {
  __shared__ float ht[64 * 129];
  int t = threadIdx.x;
  int r0 = blockIdx.x * 64;
  {
    int rr = t >> 2, q = t & 3;
    const float4* src = (const float4*)(h + (size_t)(r0 + rr) * FO + q * 32);
    float* dst = &ht[rr * 129 + q * 32];
#pragma unroll
    for (int i = 0; i < 8; ++i) {
      float4 v = src[i];
      dst[4 * i + 0] = v.x; dst[4 * i + 1] = v.y;
      dst[4 * i + 2] = v.z; dst[4 * i + 3] = v.w;
    }
  }
  __syncthreads();
  {
    int c = t >> 1, half = t & 1;
    alignas(16) _Float16 buf[32];
#pragma unroll
    for (int i = 0; i < 32; ++i) buf[i] = (_Float16)ht[(half * 32 + i) * 129 + c];
    int4* d = (int4*)(hT + (size_t)c * NN + r0 + half * 32);
#pragma unroll
    for (int i = 0; i < 4; ++i) d[i] = ((const int4*)buf)[i];
  }
  if (t < 64) {
    int row = r0 + t;
    float v1 = 0.f, v2 = 0.f;
#pragma unroll 16
    for (int c = 0; c < FO; ++c) {
      float hv = ht[t * 129 + c];
      v1 = fmaf(hv, a[c], v1);
      v2 = fmaf(hv, a[FO + c], v2);
    }
    s1[row] = v1; s2[row] = v2;
    float m = v2;
#pragma unroll
    for (int off = 1; off < 64; off <<= 1) m = fmaxf(m, __shfl_xor(m, off));
    if (t == 0) atomicMax(enc, enc_f32(m));
  }
}

// weight: w = adj>0 ? exp(leaky(s1+s2) - m) : 0, rounded to fp16;
// den accumulates the *rounded* weight in f32 for exact normalization consistency.
__device__ __forceinline__ _Float16 wel(int av, float s2v, float s1v, float mv, float& sum) {
  float tt = s1v + s2v;
  tt = fmaxf(tt, 0.01f * tt);  // leaky_relu
  float wf = (av > 0) ? __expf(tt - mv) : 0.f;
  _Float16 wh = (_Float16)wf;
  sum += (float)wh;
  return wh;
}

// ---------------- K4: fused attention x h -------------------------------------
// grid (8 splits, 128 row-blocks), 256 threads = 4 waves x 16 rows.
// LDS: double-buffered 128x32 fp16 hT tile staged via global_load_lds (width 16).
// 2-phase counted-vmcnt pipeline: stage next -> compute -> vmcnt(4) -> s_barrier.
// A (weights) computed in-register in MFMA A-fragment layout.
__global__ void __launch_bounds__(256, 4) k4_main(
    const int* __restrict__ adj, const float* __restrict__ s1g,
    const float* __restrict__ s2g, const unsigned* __restrict__ enc,
    const _Float16* __restrict__ hT,
    float* __restrict__ num_p, float* __restrict__ den_p, int jchunk) {
  __shared__ _Float16 tile[2][128 * 32];
  int t = threadIdx.x;
  int l = t & 63, wv = t >> 6;
  int l15 = l & 15, kgrp = l >> 4;
  int split = blockIdx.x;
  int r0 = blockIdx.y * 64;
  int jbeg = split * jchunk;
  int row = r0 + wv * 16 + l15;

  float c2 = dec_f32(*enc);
  float s10 = s1g[row];
  float m0 = s10 + c2; m0 = fmaxf(m0, 0.01f * m0);

  f32x4 acc[8];
#pragma unroll
  for (int cf = 0; cf < 8; ++cf) acc[cf] = (f32x4){0.f, 0.f, 0.f, 0.f};
  float sum0 = 0.f;
  const int* adjr = adj + (size_t)row * NN;

  // stage: rows wv*32 .. wv*32+31 of the 128x32 tile, 2 async 1KB calls/wave
  auto stage = [&](int b, int j0) {
    const _Float16* g0 = hT + (size_t)(wv * 32 + (l >> 2)) * NN + j0 + (l & 3) * 8;
    gl_lds16(g0, &tile[b][(wv * 32) * 32]);
    gl_lds16(g0 + (size_t)16 * NN, &tile[b][(wv * 32 + 16) * 32]);
  };

  int niter = jchunk >> 5;
  // ---- prologue: stage buf0, prefetch iter0 adj/s2 ----
  stage(0, jbeg);
  __builtin_amdgcn_sched_barrier(0);
  int jl = jbeg + kgrp * 8;
  int4 A0 = ((const int4*)(adjr + jl))[0];
  int4 A1 = ((const int4*)(adjr + jl))[1];
  float4 sa = *(const float4*)(s2g + jl);
  float4 sb = *(const float4*)(s2g + jl + 4);
  asm volatile("s_waitcnt vmcnt(4)" ::: "memory");
  __builtin_amdgcn_s_barrier();
  __builtin_amdgcn_sched_barrier(0);

  int cur = 0;
  for (int tI = 0; tI < niter; ++tI) {
    int j0 = jbeg + (tI << 5);
    bool has_next = (tI + 1 < niter);
    if (has_next) stage(cur ^ 1, j0 + 32);
    __builtin_amdgcn_sched_barrier(0);
    int4 nA0, nA1; float4 nsa, nsb;
    if (has_next) {
      int jn = j0 + 32 + kgrp * 8;
      nA0 = ((const int4*)(adjr + jn))[0];
      nA1 = ((const int4*)(adjr + jn))[1];
      nsa = *(const float4*)(s2g + jn);
      nsb = *(const float4*)(s2g + jn + 4);
    }
    // attention weights, directly in A-fragment layout (row=l15, k=kgrp*8+e)
    f16x8 af;
    af[0] = wel(A0.x, sa.x, s10, m0, sum0);
    af[1] = wel(A0.y, sa.y, s10, m0, sum0);
    af[2] = wel(A0.z, sa.z, s10, m0, sum0);
    af[3] = wel(A0.w, sa.w, s10, m0, sum0);
    af[4] = wel(A1.x, sb.x, s10, m0, sum0);
    af[5] = wel(A1.y, sb.y, s10, m0, sum0);
    af[6] = wel(A1.z, sb.z, s10, m0, sum0);
    af[7] = wel(A1.w, sb.w, s10, m0, sum0);
    // B fragments from LDS + MFMA
    f16x8 bfr[8];
#pragma unroll
    for (int cf = 0; cf < 8; ++cf)
      bfr[cf] = *(const f16x8*)&tile[cur][(cf * 16 + l15) * 32 + kgrp * 8];
#pragma unroll
    for (int cf = 0; cf < 8; ++cf)
      acc[cf] = __builtin_amdgcn_mfma_f32_16x16x32_f16(af, bfr[cf], acc[cf], 0, 0, 0);
    __builtin_amdgcn_sched_barrier(0);
    if (has_next) {
      asm volatile("s_waitcnt vmcnt(4)" ::: "memory");  // stage retired; adj/s2 stay in flight
      __builtin_amdgcn_s_barrier();
      __builtin_amdgcn_sched_barrier(0);
      A0 = nA0; A1 = nA1; sa = nsa; sb = nsb;
      cur ^= 1;
    }
  }
  // row sums: lanes kgrp 0..3 of same l15 combine
  sum0 += __shfl_xor(sum0, 16);
  sum0 += __shfl_xor(sum0, 32);
  size_t sbase = (size_t)split * NN;
  if (l < 16) den_p[sbase + r0 + wv * 16 + l] = sum0;
  // C/D layout: col = l&15, row = kgrp*4 + i
#pragma unroll
  for (int cf = 0; cf < 8; ++cf) {
#pragma unroll
    for (int i = 0; i < 4; ++i) {
      int orow = r0 + wv * 16 + kgrp * 4 + i;
      int ocol = cf * 16 + l15;
      num_p[(sbase + orow) * (size_t)FO + ocol] = acc[cf][i];
    }
  }
}

// ---------------- K5: finalize out = elu(sum(num)/sum(den)) ----------------
__global__ void k5_fin(const float* __restrict__ num_p, const float* __restrict__ den_p,
                       float* __restrict__ out, int splitk) {
  int idx = blockIdx.x * 256 + threadIdx.x;
  int row = idx >> 7;
  float num = 0.f, den = 0.f;
  for (int s = 0; s < splitk; ++s) {
    num += num_p[(size_t)s * (NN * FO) + idx];
    den += den_p[(size_t)s * NN + row];
  }
  float v = num / den;
  out[idx] = v > 0.f ? v : expm1f(v);
}

extern "C" void kernel_launch(void* const* d_in, const int* in_sizes, int n_in,
                              void* d_out, int out_size, void* d_ws, size_t ws_size,
                              hipStream_t stream) {
  const float* x   = (const float*)d_in[0];
  const int*   adj = (const int*)d_in[1];
  const float* W   = (const float*)d_in[2];
  const float* a   = (const float*)d_in[3];
  float* out = (float*)d_out;
  char* ws = (char*)d_ws;

  float*     h     = (float*)ws;                                   // 4 MB
  _Float16*  hT    = (_Float16*)(ws + ((size_t)4 << 20));          // 2 MB
  float*     s1    = (float*)(ws + ((size_t)6 << 20));             // 32 KB
  float*     s2    = (float*)(ws + ((size_t)6 << 20) + (32u << 10));
  unsigned*  enc   = (unsigned*)(ws + ((size_t)6 << 20) + (64u << 10));
  float*     den_p = (float*)(ws + ((size_t)6 << 20) + (128u << 10)); // 256 KB max
  float*     num_p = (float*)(ws + ((size_t)7 << 20));             // splitk * 4 MB

  int splitk = 8;
  while (splitk > 1 &&
         ((size_t)7 << 20) + (size_t)splitk * NN * FO * 4 > ws_size)
    splitk >>= 1;
  int jchunk = NN / splitk;

  k1_xw<<<dim3(256), dim3(256), 0, stream>>>(x, W, h, enc);
  k2_prep<<<dim3(128), dim3(256), 0, stream>>>(h, a, hT, s1, s2, enc);
  k4_main<<<dim3(splitk, 128), dim3(256), 0, stream>>>(adj, s1, s2, enc, hT,
                                                       num_p, den_p, jchunk);
  k5_fin<<<dim3((NN * FO) / 256), dim3(256), 0, stream>>>(num_p, den_p, out, splitk);
}